// Round 5
// baseline (1263.013 us; speedup 1.0000x reference)
//
#include <hip/hip_runtime.h>
#include <hip/hip_bf16.h>

// Problem constants (CrossNetMixFuxiCTR): B=16384, D=2048, L=3, E=8, R=64
#define BDIM 16384
#define DDIM 2048
#define LNUM 3
#define ENUM 8
#define NP 24            // L*E (l,e) pairs

#define NKIT 16          // K iterations: 2048 / BK, BK=128 (8 k16-windows per iter)

typedef _Float16 f16x8 __attribute__((ext_vector_type(8)));
typedef _Float16 f16x4 __attribute__((ext_vector_type(4)));
typedef float f32x16 __attribute__((ext_vector_type(16)));

// Fragment-major layout (X0f and Whf): 1024-B blocks. Block (g32, kw) holds
// rows g32*32..+31, k = kw*16..+15. Lane L (= khalf*32 + row) owns the 16-B
// chunk at offset L*16 (8 f16: k = kw*16 + khalf*8 ..+7). MFMA 32x32x16
// operand read = 64 consecutive 16-B chunks (coalesced global dwordx4 or
// conflict-free contiguous ds_read_b128).

// ===== prep: fused cvt_w (blocks >= GATE_BLOCKS) + gate/X0f (blocks < GATE_BLOCKS) =====
#define GATE_BLOCKS 256   // 64 rows each
__global__ __launch_bounds__(256, 4) void prep_kernel(
    const float* __restrict__ X0, const float* __restrict__ U,
    const float* __restrict__ V, const float* __restrict__ Wg,
    float* __restrict__ G, _Float16* __restrict__ X0f, _Float16* __restrict__ Whf) {
    const int tid = (int)threadIdx.x;
    if (blockIdx.x >= GATE_BLOCKS) {
        // ---- cvt U,V -> Whf fragment-major, fully coalesced writes ----
        int cidx = (blockIdx.x - GATE_BLOCKS) * 256 + tid;   // one 16-B chunk
        int col   = cidx & 31;           // row within 32-group
        int khalf = (cidx >> 5) & 1;
        int kw    = (cidx >> 6) & 127;
        int gn    = (cidx >> 13) & 3;
        int p     = cidx >> 15;
        int row128 = gn * 32 + col;
        const float* src = (row128 < 64)
            ? (U + ((size_t)(p * 64 + row128) * DDIM + kw * 16 + khalf * 8))
            : (V + ((size_t)(p * 64 + (row128 - 64)) * DDIM + kw * 16 + khalf * 8));
        float4 a = ((const float4*)src)[0];
        float4 b = ((const float4*)src)[1];
        f16x8 h = { (_Float16)a.x, (_Float16)a.y, (_Float16)a.z, (_Float16)a.w,
                    (_Float16)b.x, (_Float16)b.y, (_Float16)b.z, (_Float16)b.w };
        ((f16x8*)Whf)[cidx] = h;   // cidx == ((p*4+gn)*128+kw)*64 + khalf*32 + col
        return;
    }
    // ---- gate: G[j][b] = X0[b].Wg[j] (fp32) + X0 -> X0f f16 fragment-major ----
    // 64 rows/block; thread: rows (r0, r0+32), k-slice q = tid&7.
    __shared__ float Wgs[NP * 256];   // 24 KB
    const int rq = tid >> 3;           // 0..31
    const int q  = tid & 7;
    const int r0 = blockIdx.x * 64 + rq;
    const int g32a = blockIdx.x * 2, g32b_ = g32a + 1;

    float acc[2][NP];
#pragma unroll
    for (int r = 0; r < 2; ++r)
#pragma unroll
        for (int j = 0; j < NP; ++j) acc[r][j] = 0.f;

    const float4* x0p = (const float4*)(X0 + (size_t)r0 * DDIM);
    const float4* x1p = (const float4*)(X0 + (size_t)(r0 + 32) * DDIM);

    for (int k0 = 0; k0 < DDIM; k0 += 256) {
        __syncthreads();
#pragma unroll
        for (int t = tid; t < NP * 64; t += 256)
            ((float4*)Wgs)[t] =
                ((const float4*)Wg)[(size_t)(t >> 6) * (DDIM / 4) + (k0 >> 2) + (t & 63)];
        __syncthreads();
#pragma unroll 2
        for (int i = 0; i < 4; ++i) {
            int f8l = i * 8 + q;                 // 8-f16 chunk within 256-k window
            int gf4 = (k0 >> 2) + f8l * 2;       // global float4 col
            float4 xa = x0p[gf4], xb = x0p[gf4 + 1];
            float4 ya = x1p[gf4], yb = x1p[gf4 + 1];
            int f8g = (k0 >> 3) + f8l;
            int kw = f8g >> 1, khalf = f8g & 1;
            f16x8 h0 = { (_Float16)xa.x, (_Float16)xa.y, (_Float16)xa.z, (_Float16)xa.w,
                         (_Float16)xb.x, (_Float16)xb.y, (_Float16)xb.z, (_Float16)xb.w };
            f16x8 h1 = { (_Float16)ya.x, (_Float16)ya.y, (_Float16)ya.z, (_Float16)ya.w,
                         (_Float16)yb.x, (_Float16)yb.y, (_Float16)yb.z, (_Float16)yb.w };
            ((f16x8*)X0f)[((size_t)(g32a * 128 + kw)) * 64 + khalf * 32 + rq] = h0;
            ((f16x8*)X0f)[((size_t)(g32b_ * 128 + kw)) * 64 + khalf * 32 + rq] = h1;
#pragma unroll
            for (int j = 0; j < NP; ++j) {
                float4 wa = ((const float4*)(Wgs + j * 256))[f8l * 2];
                float4 wb = ((const float4*)(Wgs + j * 256))[f8l * 2 + 1];
                acc[0][j] += xa.x * wa.x + xa.y * wa.y + xa.z * wa.z + xa.w * wa.w
                           + xb.x * wb.x + xb.y * wb.y + xb.z * wb.z + xb.w * wb.w;
                acc[1][j] += ya.x * wa.x + ya.y * wa.y + ya.z * wa.z + ya.w * wa.w
                           + yb.x * wb.x + yb.y * wb.y + yb.z * wb.z + yb.w * wb.w;
            }
        }
    }
#pragma unroll
    for (int r = 0; r < 2; ++r)
#pragma unroll
        for (int j = 0; j < NP; ++j) {
            float v = acc[r][j];
            v += __shfl_xor(v, 1);
            v += __shfl_xor(v, 2);
            v += __shfl_xor(v, 4);
            if (q == 0) G[(size_t)j * BDIM + r0 + r * 32] = v;
        }
}

// ===== gemm (BK=128, A direct-to-VGPR, B LDS dbuf) + fused per-g32 epilogue =====
// 1D grid 1536: p = bx%24 (p-fast => same-p blocks land on the same XCD, B slab
// L2-resident; 24 consecutive blocks share the A slab). Block: 4 waves, 256 rows.
// Wave: 64 rows x 128 cols, acc[2][4] f32x16. Per kiter: 64 MFMA (~1033 cyc/SIMD)
// per barrier; aF half-kiter ping-pong + next-B staging drained by the barrier
// with >=516-cyc issue-ahead vs ~200-cyc L2 latency => small drain.
// After T: atomicAdd per 32-row group; 24th finisher runs that group's epilogue.
__global__ __launch_bounds__(256, 2) void gemm_epi_kernel(
    const _Float16* __restrict__ X0f,  // fragment-major A
    const _Float16* __restrict__ Whf,  // fragment-major B
    const float* __restrict__ X0,
    const float* __restrict__ G,
    const float* __restrict__ bg,
    float* __restrict__ T,             // [NP][BDIM]
    unsigned int* __restrict__ cnt,    // [BDIM/32] zeroed on stream
    float* __restrict__ out)
{
    const int bx   = (int)blockIdx.x;
    const int p    = bx % NP;
    const int xb   = bx / NP;
    const int m0   = xb * 256;
    const int tid  = (int)threadIdx.x;
    const int wave = tid >> 6;
    const int lane = tid & 63;

    __shared__ _Float16 Bs[2 * 32 * 512];   // 64 KB: 2 bufs x (4 gn x 8 kw) x 1024 B
    __shared__ float s_sh[32];
    __shared__ unsigned int won_sh;
    if (tid == 0) won_sh = 0u;

    const int g32b = xb * 8 + wave * 2;     // wave's first 32-row group
    const _Float16* Bp = Whf + ((size_t)(p * 4 + wave) * 128) * 512;  // wave stages gn=wave

    f32x16 acc[2][4];                       // [mt][gn]
#pragma unroll
    for (int i = 0; i < 2; ++i)
#pragma unroll
        for (int j = 0; j < 4; ++j) acc[i][j] = (f32x16)(0.f);

    f16x8 aF[2][8];                         // [half][mt*4+i]

    // prologue: stage B kiter0 (kw 0..7), load aF[0] (kw 0..3)
#pragma unroll
    for (int kw = 0; kw < 8; ++kw)
        __builtin_amdgcn_global_load_lds(
            (const __attribute__((address_space(1))) void*)(Bp + (size_t)kw * 512 + lane * 8),
            (__attribute__((address_space(3))) void*)&Bs[(wave * 8 + kw) * 512], 16, 0, 0);
#pragma unroll
    for (int mt = 0; mt < 2; ++mt)
#pragma unroll
        for (int i = 0; i < 4; ++i)
            aF[0][mt * 4 + i] = *(const f16x8*)(
                X0f + ((size_t)((g32b + mt) * 128 + i)) * 512 + lane * 8);
    __syncthreads();

#pragma unroll 1
    for (int it = 0; it < NKIT; ++it) {
        const int cur = it & 1, nxt = cur ^ 1;
        const int kb = it * 8;
        if (it != NKIT - 1) {
#pragma unroll
            for (int kw = 0; kw < 8; ++kw)
                __builtin_amdgcn_global_load_lds(
                    (const __attribute__((address_space(1))) void*)(
                        Bp + (size_t)(kb + 8 + kw) * 512 + lane * 8),
                    (__attribute__((address_space(3))) void*)&Bs[(nxt * 32 + wave * 8 + kw) * 512],
                    16, 0, 0);
        }
        // load this kiter's half1 A frags (budget: half0's 32 MFMA)
#pragma unroll
        for (int mt = 0; mt < 2; ++mt)
#pragma unroll
            for (int i = 0; i < 4; ++i)
                aF[1][mt * 4 + i] = *(const f16x8*)(
                    X0f + ((size_t)((g32b + mt) * 128 + kb + 4 + i)) * 512 + lane * 8);
        // MFMA half0: kw kb..kb+3
#pragma unroll
        for (int i = 0; i < 4; ++i) {
            f16x8 bF[4];
#pragma unroll
            for (int gn = 0; gn < 4; ++gn)
                bF[gn] = *(const f16x8*)&Bs[(cur * 32 + gn * 8 + i) * 512 + lane * 8];
#pragma unroll
            for (int mt = 0; mt < 2; ++mt)
#pragma unroll
                for (int gn = 0; gn < 4; ++gn)
                    acc[mt][gn] = __builtin_amdgcn_mfma_f32_32x32x16_f16(
                        aF[0][mt * 4 + i], bF[gn], acc[mt][gn], 0, 0, 0);
        }
        // load next kiter's half0 A frags (budget: half1's 32 MFMA + barrier)
        if (it != NKIT - 1) {
#pragma unroll
            for (int mt = 0; mt < 2; ++mt)
#pragma unroll
                for (int i = 0; i < 4; ++i)
                    aF[0][mt * 4 + i] = *(const f16x8*)(
                        X0f + ((size_t)((g32b + mt) * 128 + kb + 8 + i)) * 512 + lane * 8);
        }
        // MFMA half1: kw kb+4..kb+7
#pragma unroll
        for (int i = 0; i < 4; ++i) {
            f16x8 bF[4];
#pragma unroll
            for (int gn = 0; gn < 4; ++gn)
                bF[gn] = *(const f16x8*)&Bs[(cur * 32 + gn * 8 + 4 + i) * 512 + lane * 8];
#pragma unroll
            for (int mt = 0; mt < 2; ++mt)
#pragma unroll
                for (int gn = 0; gn < 4; ++gn)
                    acc[mt][gn] = __builtin_amdgcn_mfma_f32_32x32x16_f16(
                        aF[1][mt * 4 + i], bF[gn], acc[mt][gn], 0, 0, 0);
        }
        __syncthreads();
    }

    // C/D layout (32x32x16): col = lane&31, row = (reg&3) + 8*(reg>>2) + 4*(lane>>5).
    // T[p][m] = sum_r PU*PV: in-lane acc[mt][g]*acc[mt][g+2] + butterfly over 32 cols.
#pragma unroll
    for (int mt = 0; mt < 2; ++mt) {
#pragma unroll
        for (int reg = 0; reg < 16; ++reg) {
            float tp = acc[mt][0][reg] * acc[mt][2][reg]
                     + acc[mt][1][reg] * acc[mt][3][reg];
            tp += __shfl_xor(tp, 1);
            tp += __shfl_xor(tp, 2);
            tp += __shfl_xor(tp, 4);
            tp += __shfl_xor(tp, 8);
            tp += __shfl_xor(tp, 16);
            if ((lane & 31) == 0) {
                int row = (reg & 3) + 8 * (reg >> 2) + 4 * (lane >> 5);
                T[(size_t)p * BDIM + m0 + wave * 64 + mt * 32 + row] = tp;
            }
        }
    }

    // ---- fused epilogue: 24th finisher of each 32-row group scales & writes ----
    __threadfence();            // release our T writes
    __syncthreads();
    if (tid < 8) {
        unsigned old = atomicAdd(&cnt[xb * 8 + tid], 1u);
        if (old == NP - 1) atomicOr(&won_sh, 1u << tid);
    }
    __syncthreads();
    unsigned won = won_sh;
    if (won) __threadfence();   // acquire other blocks' T writes
    while (won) {
        int qg = __ffs(won) - 1;
        won &= won - 1u;
        int r0 = m0 + qg * 32;
        if (tid < 32) {
            int b = r0 + tid;
            float s = 1.f;
#pragma unroll
            for (int l = 0; l < LNUM; ++l) {
                float logit[ENUM];
                float mx = -1e30f;
#pragma unroll
                for (int e = 0; e < ENUM; ++e) {
                    int j = l * ENUM + e;
                    float g = s * G[(size_t)j * BDIM + b] + bg[j];
                    logit[e] = g;
                    mx = fmaxf(mx, g);
                }
                float den = 0.f, num = 0.f;
                float s2 = s * s;
#pragma unroll
                for (int e = 0; e < ENUM; ++e) {
                    int j = l * ENUM + e;
                    float w = __expf(logit[e] - mx);
                    den += w;
                    num += w * (s2 * T[(size_t)j * BDIM + b]);
                }
                s += num / den;
            }
            s_sh[tid] = s;
        }
        __syncthreads();
        for (int idx = tid; idx < 32 * 512; idx += 256) {   // 32 rows x 512 float4
            int r = idx >> 9;
            int c = idx & 511;
            float s = s_sh[r];
            float4 x = ((const float4*)(X0 + (size_t)(r0 + r) * DDIM))[c];
            x.x *= s; x.y *= s; x.z *= s; x.w *= s;
            ((float4*)(out + (size_t)(r0 + r) * DDIM))[c] = x;
        }
        __syncthreads();   // s_sh reuse safety for next won group
    }
}

extern "C" void kernel_launch(void* const* d_in, const int* in_sizes, int n_in,
                              void* d_out, int out_size, void* d_ws, size_t ws_size,
                              hipStream_t stream) {
    const float* X0 = (const float*)d_in[0];
    const float* U  = (const float*)d_in[1];
    const float* V  = (const float*)d_in[2];
    const float* Wg = (const float*)d_in[3];
    const float* bg = (const float*)d_in[4];
    float* out = (float*)d_out;

    // workspace layout (~82.84 MB)
    char* ws = (char*)d_ws;
    _Float16* X0f = (_Float16*)ws;                                   // 67108864 B
    _Float16* Whf = (_Float16*)(ws + 67108864ull);                   // 12582912 B
    float* T      = (float*)(ws + 67108864ull + 12582912ull);        // 1572864 B
    float* G      = (float*)(ws + 67108864ull + 12582912ull + 1572864ull);  // 1572864 B
    unsigned int* cnt = (unsigned int*)(ws + 67108864ull + 12582912ull + 2 * 1572864ull);

    hipMemsetAsync((void*)cnt, 0, (BDIM / 32) * sizeof(unsigned int), stream);
    // prep: 256 gate blocks + 3072 cvt blocks
    prep_kernel<<<dim3(GATE_BLOCKS + NP * 128 * 256 / 256), dim3(256), 0, stream>>>(
        X0, U, V, Wg, G, X0f, Whf);
    gemm_epi_kernel<<<dim3((BDIM / 256) * NP), dim3(256), 0, stream>>>(
        X0f, Whf, X0, G, bg, T, cnt, out);
}